// Round 20
// baseline (98.943 us; speedup 1.0000x reference)
//
#include <hip/hip_runtime.h>
#include <stdint.h>

#define S_LEN 2048
#define EMB   768
#define NHEAD 12
#define HDIM  64

typedef __attribute__((ext_vector_type(8)))  __bf16       bf16x8;
typedef __attribute__((ext_vector_type(4)))  float        f32x4;
typedef __attribute__((ext_vector_type(16))) float        f32x16;
typedef __attribute__((ext_vector_type(2)))  unsigned int u32x2;
typedef __attribute__((ext_vector_type(4)))  unsigned int u32x4;

__device__ __forceinline__ uint16_t f32_to_bf16(float f) {
  uint32_t u = __float_as_uint(f);
  u += 0x7FFFu + ((u >> 16) & 1u);           // round-to-nearest-even
  return (uint16_t)(u >> 16);
}

__device__ __forceinline__ uint32_t cvtpk_bf16(float lo, float hi) {
  uint32_t r;
  asm("v_cvt_pk_bf16_f32 %0, %1, %2" : "=v"(r) : "v"(lo), "v"(hi));
  return r;
}

#if __has_builtin(__builtin_amdgcn_exp2f)
#define EXP2F(x) __builtin_amdgcn_exp2f(x)
#else
#define EXP2F(x) exp2f(x)
#endif

#define ZERO16 {0.f,0.f,0.f,0.f,0.f,0.f,0.f,0.f,0.f,0.f,0.f,0.f,0.f,0.f,0.f,0.f}

// XOR swizzle for [rows][64] bf16 LDS tiles (idx in ushort units).
__device__ __forceinline__ int swz64(int idx) {
  return idx ^ (((idx >> 6) & 7) << 3);
}

// async global->LDS, 16B per lane; dest must be linear (wave base + lane*16)
__device__ __forceinline__ void gload16(uint16_t* lds, const uint16_t* g) {
  __builtin_amdgcn_global_load_lds((const __attribute__((address_space(1))) void*)g,
                                   (__attribute__((address_space(3))) void*)lds, 16, 0, 0);
}

// ---------------- fused fp32 -> bf16 convert (verified r12) ----------------
__global__ __launch_bounds__(256) void cvt_all(const float4* __restrict__ i0, ushort4* __restrict__ o0, int n0,
                                               const float4* __restrict__ i1, ushort4* __restrict__ o1, int n1,
                                               const float4* __restrict__ i2, ushort4* __restrict__ o2, int n2) {
  int gid = blockIdx.x * blockDim.x + threadIdx.x;
  const float4* src;
  ushort4* dst;
  int idx;
  if (gid < n0)           { src = i0; dst = o0; idx = gid; }
  else if (gid < n0 + n1) { src = i1; dst = o1; idx = gid - n0; }
  else if (gid < n0 + n1 + n2) { src = i2; dst = o2; idx = gid - n0 - n1; }
  else return;
  float4 v = src[idx];
  ushort4 o;
  o.x = f32_to_bf16(v.x); o.y = f32_to_bf16(v.y);
  o.z = f32_to_bf16(v.z); o.w = f32_to_bf16(v.w);
  dst[idx] = o;
}

// ---------------- mask scan (parallel, verified r16): cpos, compact bias, tile counts ----------------
__global__ __launch_bounds__(256) void mask_scan(const int* __restrict__ mask,
                                                 int* __restrict__ cpos,
                                                 float* __restrict__ mbc,
                                                 int* __restrict__ ntp,
                                                 int* __restrict__ nbp) {
  const int b    = blockIdx.x;
  const int t    = threadIdx.x;
  const int lane = t & 63;
  const int wvi  = t >> 6;
  __shared__ int wsum[4];
  int m[8], u = 0;
#pragma unroll
  for (int j = 0; j < 8; j++) {
    m[j] = mask[b * S_LEN + t * 8 + j];
    u += (m[j] == 0);
  }
  int x = u;
#pragma unroll
  for (int off = 1; off < 64; off <<= 1) {
    int v = __shfl_up(x, off);
    if (lane >= off) x += v;
  }
  if (lane == 63) wsum[wvi] = x;
  __syncthreads();
  int wbase = 0;
#pragma unroll
  for (int i = 0; i < 4; i++) wbase += (i < wvi) ? wsum[i] : 0;
  const int nb = wsum[0] + wsum[1] + wsum[2] + wsum[3];
  int base = wbase + x - u;                 // exclusive prefix for this thread
#pragma unroll
  for (int j = 0; j < 8; j++) {
    int sc = (m[j] == 0) ? base : -1;
    if (m[j] == 0) base++;
    cpos[b * S_LEN + t * 8 + j] = sc;
    mbc[b * S_LEN + t * 8 + j] = ((t * 8 + j) < nb) ? 0.0f : -1e30f;
  }
  if (t == 0) {
    ntp[b] = ((nb + 63) & ~63) >> 6;
    nbp[b] = nb;
  }
}

// ---------------- pad fill (verified r16): zero pad rows of K / pad cols of V^T ----------------
__global__ __launch_bounds__(256) void pad_fill(const int* __restrict__ nbp,
                                                uint16_t* __restrict__ kb,
                                                uint16_t* __restrict__ vb) {
  const int b = blockIdx.x / NHEAD, h = blockIdx.x % NHEAD;
  const int t = threadIdx.x;
  const int nb = nbp[b];
  const int padN = (nb + 63) & ~63;
  const int npad = padN - nb;
  for (int idx = t; idx < npad * HDIM; idx += 256) {
    int row = idx >> 6, d = idx & (HDIM - 1);
    kb[(((size_t)b * NHEAD + h) * S_LEN + nb + row) * HDIM + d] = 0;
    vb[(((size_t)b * NHEAD + h) * HDIM + d) * S_LEN + nb + row] = 0;
  }
}

// ---------------- QKV GEMM, G=3 bn-grouping: BM=128, BN_eff=192, 384 blocks ----------------
// Per K-step: stage A ONCE + 3 B-tiles (40KB -> 128x192 output). Total staged bytes
// 339 -> 188MB, attacking the measured ~12-16 B/cy/CU global_load_lds ingest cap
// (the invariant across all six null qkv experiments). Group is entirely Q/K/V
// (cQ = bng/4), so the verified block-uniform epilogue applies per g.
__global__ __launch_bounds__(256) void qkv_gemm(const uint16_t* __restrict__ A,
                                                const uint16_t* __restrict__ W,
                                                const float* __restrict__ bias,
                                                const int* __restrict__ cpos,
                                                uint16_t* __restrict__ qb,
                                                uint16_t* __restrict__ kb,
                                                uint16_t* __restrict__ vb) {
  __shared__ __align__(16) uint16_t As[128 * 64];      // 16KB
  __shared__ __align__(16) uint16_t Bs[3][64 * 64];    // 24KB
  const int t    = threadIdx.x;
  const int lane = t & 63;
  const int wv   = t >> 6;
  const int wr   = wv >> 1, wc = wv & 1;
  // bijective XCD swizzle, bn-fast: 384 = 8 * 48, 48 = 4 bm * 12 bng
  const int wg   = (blockIdx.x & 7) * 48 + (blockIdx.x >> 3);
  const int bm   = wg / 12;                  // 32 M tiles (128 rows)
  const int bng  = wg % 12;                  // 12 bn groups (192 cols each)
  const int cQ   = bng >> 2;                 // 0=Q, 1=K, 2=V (block-uniform)

  const uint16_t* Ag = A + (size_t)bm * 128 * 768;
  const uint16_t* Wg = W + (size_t)(bng * 3) * 64 * 768;

  f32x4 zf = {0.f, 0.f, 0.f, 0.f};
  f32x4 acc[3][4][2];
#pragma unroll
  for (int g = 0; g < 3; g++)
#pragma unroll
    for (int m = 0; m < 4; m++)
#pragma unroll
      for (int n = 0; n < 2; n++) acc[g][m][n] = zf;

  for (int k0 = 0; k0 < 768; k0 += 64) {
#pragma unroll
    for (int j = 0; j < 4; j++) {            // A tile: 1024 chunks
      int p = j * 256 + t;
      int r = p >> 3, x = p & 7;
      int scol = (x ^ (r & 7)) << 3;
      gload16(&As[p * 8], Ag + (size_t)r * 768 + k0 + scol);
    }
#pragma unroll
    for (int g = 0; g < 3; g++)              // 3 B tiles: 512 chunks each
#pragma unroll
      for (int j = 0; j < 2; j++) {
        int p = j * 256 + t;
        int r = p >> 3, x = p & 7;
        int scol = (x ^ (r & 7)) << 3;
        gload16(&Bs[g][p * 8], Wg + (size_t)(g * 64 + r) * 768 + k0 + scol);
      }
    __syncthreads();
#pragma unroll
    for (int kk = 0; kk < 2; kk++) {
      const int kc = kk * 32 + (lane >> 4) * 8;
      bf16x8 af[4];
#pragma unroll
      for (int m = 0; m < 4; m++)
        af[m] = *reinterpret_cast<const bf16x8*>(&As[swz64((wr * 64 + m * 16 + (lane & 15)) * 64 + kc)]);
#pragma unroll
      for (int g = 0; g < 3; g++) {
        bf16x8 bf[2];
#pragma unroll
        for (int n = 0; n < 2; n++)
          bf[n] = *reinterpret_cast<const bf16x8*>(&Bs[g][swz64((wc * 32 + n * 16 + (lane & 15)) * 64 + kc)]);
#pragma unroll
        for (int m = 0; m < 4; m++)
#pragma unroll
          for (int n = 0; n < 2; n++)
            acc[g][m][n] = __builtin_amdgcn_mfma_f32_16x16x32_bf16(af[m], bf[n], acc[g][m][n], 0, 0, 0);
      }
    }
    __syncthreads();
  }

  int scv[4][4];
  if (cQ != 0) {
#pragma unroll
    for (int m = 0; m < 4; m++)
#pragma unroll
      for (int r = 0; r < 4; r++) {
        int i = bm * 128 + wr * 64 + m * 16 + (lane >> 4) * 4 + r;
        scv[m][r] = cpos[(i >> 11) * S_LEN + (i & 2047)];
      }
  }
#pragma unroll
  for (int g = 0; g < 3; g++) {
#pragma unroll
    for (int n = 0; n < 2; n++) {
      const int f   = (bng * 3 + g) * 64 + wc * 32 + n * 16 + (lane & 15);
      const float bv = bias[f];
      const int rem = f - cQ * 768;
      const int h   = rem >> 6, d = rem & 63;
      const float scl = (cQ == 0) ? 0.125f * 1.44269504f : 1.0f;  // SCALE*log2e folded into Q
#pragma unroll
      for (int m = 0; m < 4; m++) {
#pragma unroll
        for (int r = 0; r < 4; r++) {
          int i = bm * 128 + wr * 64 + m * 16 + (lane >> 4) * 4 + r;
          int b = i >> 11, s = i & 2047;
          uint16_t val = f32_to_bf16((acc[g][m][n][r] + bv) * scl);
          if (cQ == 0) {
            qb[(((size_t)b * NHEAD + h) * S_LEN + s) * HDIM + d] = val;
          } else {
            int sc = scv[m][r];
            if (sc >= 0) {
              if (cQ == 1)
                kb[(((size_t)b * NHEAD + h) * S_LEN + sc) * HDIM + d] = val;
              else
                vb[(((size_t)b * NHEAD + h) * HDIM + d) * S_LEN + sc] = val;  // V transposed
            }
          }
        }
      }
    }
  }
}

// ---------------- Flash attention (verified r16): compacted keys, tail-only bias ----------------
__global__ __launch_bounds__(256, 3) void attn_kernel(const uint16_t* __restrict__ Q,   // [BH][S][D], pre-scaled
                                                      const uint16_t* __restrict__ Kb,  // [BH][Sc][D] compacted
                                                      const uint16_t* __restrict__ Vb,  // [BH][D][Sc] compacted
                                                      const float* __restrict__ mbc,    // [B][S] compact bias
                                                      const int* __restrict__ ntp,      // [B] tile count
                                                      uint16_t* __restrict__ X) {       // [B][S][E] bf16
  __shared__ __align__(16) uint16_t Kd[2][64 * 64];
  __shared__ __align__(16) uint16_t Vd[2][64 * 64];   // [d][key]
  __shared__ __align__(16) float    mb_s[S_LEN];
  __shared__ float Lc[2][32];

  const int t    = threadIdx.x;
  const int lane = t & 63;
  const int hl   = lane >> 5;                   // lane half
  const int q31  = lane & 31;
  const int wv   = t >> 6;
  const int qg   = wv & 1;                      // q-group
  const int kh   = wv >> 1;                     // key-half
  // bijective XCD swizzle: 768 = 8 * 96; each XCD gets 3 whole heads (L2-fit K/V)
  const int wg   = (blockIdx.x & 7) * 96 + (blockIdx.x >> 3);
  const int qblk = wg & 31;
  const int bh   = wg >> 5;
  const int b    = bh / NHEAD, hd = bh % NHEAD;

  const uint16_t* Qh = Q  + (size_t)bh * S_LEN * HDIM;
  const uint16_t* Kh = Kb + (size_t)bh * S_LEN * HDIM;
  const uint16_t* Vh = Vb + (size_t)bh * HDIM * S_LEN;
  const int q0 = qblk * 64 + qg * 32;
  const int nt = ntp[b];

  // compact bias preload (8 keys/thread, coalesced float4)
  {
    float4 f0 = *reinterpret_cast<const float4*>(&mbc[b * S_LEN + t * 8]);
    float4 f1 = *reinterpret_cast<const float4*>(&mbc[b * S_LEN + t * 8 + 4]);
    *reinterpret_cast<float4*>(&mb_s[t * 8])     = f0;
    *reinterpret_cast<float4*>(&mb_s[t * 8 + 4]) = f1;
  }

  // Q as B-fragments: col=q31, k=d=16s+8hl+j
  bf16x8 qf[4];
#pragma unroll
  for (int s = 0; s < 4; s++)
    qf[s] = *reinterpret_cast<const bf16x8*>(Qh + (size_t)(q0 + q31) * HDIM + 16 * s + 8 * hl);

  f32x16 oacc[2] = {ZERO16, ZERO16};
  float lsum = 0.f;

  const uint16_t* kga[2]; const uint16_t* vga[2]; int lof[2];
#pragma unroll
  for (int j = 0; j < 2; j++) {
    int p = j * 256 + t, r = p >> 3, x = p & 7;
    int scol = (x ^ (r & 7)) << 3;
    kga[j] = Kh + (size_t)r * HDIM + scol;
    vga[j] = Vh + (size_t)r * S_LEN + scol;
    lof[j] = p * 8;
  }
  auto stage = [&](int nb2, int it2) {   // 4 vmem instructions per thread
#pragma unroll
    for (int j = 0; j < 2; j++) {
      gload16(&Kd[nb2][lof[j]], kga[j] + it2 * 64 * HDIM);
      gload16(&Vd[nb2][lof[j]], vga[j] + it2 * 64);
    }
  };

  stage(0, 0);
  __syncthreads();                       // prologue: full drain, bias + buf0 ready

#pragma unroll 2
  for (int it = 0; it < nt; ++it) {
    const int cur = it & 1;
    __builtin_amdgcn_s_barrier();        // A: all waves done compute(it-1) -> buf cur^1 free
    __builtin_amdgcn_sched_barrier(0);
    if (it + 1 < nt) {
      stage(cur ^ 1, it + 1);            // next-tile loads: stay in flight across B
      asm volatile("s_waitcnt vmcnt(4)" ::: "memory");   // my tile-it loads done
    } else {
      asm volatile("s_waitcnt vmcnt(0)" ::: "memory");
    }
    __builtin_amdgcn_s_barrier();        // B: buf cur staged block-wide
    __builtin_amdgcn_sched_barrier(0);

    // QK^T (swapped): scc[reg] = S[key_loc=(reg&3)+8*(reg>>2)+4*hl][q31]
    f32x16 scc = ZERO16;
    __builtin_amdgcn_s_setprio(1);
#pragma unroll
    for (int s = 0; s < 4; s++) {
      bf16x8 kf = *reinterpret_cast<const bf16x8*>(&Kd[cur][swz64((kh * 32 + q31) * 64 + 16 * s + 8 * hl)]);
      scc = __builtin_amdgcn_mfma_f32_32x32x16_bf16(kf, qf[s], scc, 0, 0, 0);
    }
    __builtin_amdgcn_s_setprio(0);

    // exp2 + per-lane sum; bias only on the tail tile (compacted keys have bias 0)
    uint32_t w[4][2];
    if (it == nt - 1) {
#pragma unroll
      for (int s2 = 0; s2 < 4; s2++) {
        f32x4 mbv = *reinterpret_cast<const f32x4*>(&mb_s[it * 64 + kh * 32 + s2 * 8 + hl * 4]);
        float p0 = EXP2F(scc[4 * s2 + 0] + mbv[0]);
        float p1 = EXP2F(scc[4 * s2 + 1] + mbv[1]);
        float p2 = EXP2F(scc[4 * s2 + 2] + mbv[2]);
        float p3 = EXP2F(scc[4 * s2 + 3] + mbv[3]);
        lsum += (p0 + p1) + (p2 + p3);
        w[s2][0] = cvtpk_bf16(p0, p1);
        w[s2][1] = cvtpk_bf16(p2, p3);
      }
    } else {
#pragma unroll
      for (int s2 = 0; s2 < 4; s2++) {
        float p0 = EXP2F(scc[4 * s2 + 0]);
        float p1 = EXP2F(scc[4 * s2 + 1]);
        float p2 = EXP2F(scc[4 * s2 + 2]);
        float p3 = EXP2F(scc[4 * s2 + 3]);
        lsum += (p0 + p1) + (p2 + p3);
        w[s2][0] = cvtpk_bf16(p0, p1);
        w[s2][1] = cvtpk_bf16(p2, p3);
      }
    }

    // redistribute P into PV B-fragments: pb[ks][j] = P[16ks+8hl+j][q31]
    bf16x8 pb[2];
#pragma unroll
    for (int ks = 0; ks < 2; ks++) {
      u32x2 r0 = __builtin_amdgcn_permlane32_swap(w[2 * ks][0], w[2 * ks + 1][0], false, false);
      u32x2 r1 = __builtin_amdgcn_permlane32_swap(w[2 * ks][1], w[2 * ks + 1][1], false, false);
      u32x4 uu;
      uu.x = r0.x; uu.y = r1.x; uu.z = r0.y; uu.w = r1.y;
      pb[ks] = __builtin_bit_cast(bf16x8, uu);
    }

    // PV (swapped): O^T[d][q] += V^T[d][k] * P[k][q]
    __builtin_amdgcn_s_setprio(1);
#pragma unroll
    for (int mt = 0; mt < 2; mt++)
#pragma unroll
      for (int ks = 0; ks < 2; ks++) {
        bf16x8 vf = *reinterpret_cast<const bf16x8*>(&Vd[cur][swz64((mt * 32 + q31) * 64 + kh * 32 + ks * 16 + hl * 8)]);
        oacc[mt] = __builtin_amdgcn_mfma_f32_32x32x16_bf16(vf, pb[ks], oacc[mt], 0, 0, 0);
      }
    __builtin_amdgcn_s_setprio(0);
  }

  // per-wave row sum for column q31
  lsum += __shfl_xor(lsum, 32);

  __syncthreads();   // nt may be odd: all waves done reading buf0 before Oc alias write

  // combine key-half partials: kh=1 writes O^T and l, kh=0 finishes
  float* Oc = qg ? (float*)&Vd[0][0] : (float*)&Kd[0][0];   // [64 d][32 q]
  if (kh == 1) {
#pragma unroll
    for (int mt = 0; mt < 2; mt++)
#pragma unroll
      for (int e = 0; e < 16; e++) {
        int d = mt * 32 + (e & 3) + (e >> 2) * 8 + hl * 4;
        Oc[d * 32 + q31] = oacc[mt][e];
      }
    if (hl == 0) Lc[qg][q31] = lsum;
  }
  __syncthreads();
  if (kh == 0) {
    float linv = 1.0f / (lsum + Lc[qg][q31]);
    uint16_t* Xr = X + ((size_t)b * S_LEN + q0 + q31) * EMB + hd * HDIM;
#pragma unroll
    for (int mt = 0; mt < 2; mt++)
#pragma unroll
      for (int s2 = 0; s2 < 4; s2++) {
        int d0 = mt * 32 + s2 * 8 + hl * 4;
        float v0 = (oacc[mt][4 * s2 + 0] + Oc[(d0 + 0) * 32 + q31]) * linv;
        float v1 = (oacc[mt][4 * s2 + 1] + Oc[(d0 + 1) * 32 + q31]) * linv;
        float v2 = (oacc[mt][4 * s2 + 2] + Oc[(d0 + 2) * 32 + q31]) * linv;
        float v3 = (oacc[mt][4 * s2 + 3] + Oc[(d0 + 3) * 32 + q31]) * linv;
        uint2 ww;
        ww.x = cvtpk_bf16(v0, v1);
        ww.y = cvtpk_bf16(v2, v3);
        *reinterpret_cast<uint2*>(Xr + d0) = ww;
      }
  }
}

// ---------------- Proj GEMM (verified r17): 64x64 tiles, bn-fast XCD decode ----------------
__global__ __launch_bounds__(256) void proj_gemm(const uint16_t* __restrict__ A,
                                                 const uint16_t* __restrict__ W,
                                                 const float* __restrict__ bias,
                                                 float* __restrict__ out) {
  __shared__ __align__(16) uint16_t As[64 * 64];
  __shared__ __align__(16) uint16_t Bs[64 * 64];
  const int t    = threadIdx.x;
  const int lane = t & 63;
  const int wv   = t >> 6;
  const int wr   = wv >> 1, wc = wv & 1;
  // bijective XCD swizzle, bn-fast: 768 = 8 * 96, 96 = 8 bm * 12 bn
  const int wg   = (blockIdx.x & 7) * 96 + (blockIdx.x >> 3);
  const int bm   = wg / 12;                  // 64 M tiles; 8 per XCD
  const int bn   = wg % 12;                  // 12 N tiles; all per XCD

  const uint16_t* Ag = A + (size_t)bm * 64 * 768;
  const uint16_t* Wg = W + (size_t)bn * 64 * 768;

  f32x4 zf = {0.f, 0.f, 0.f, 0.f};
  f32x4 acc[2][2];
#pragma unroll
  for (int m = 0; m < 2; m++)
#pragma unroll
    for (int n = 0; n < 2; n++) acc[m][n] = zf;

  for (int k0 = 0; k0 < 768; k0 += 64) {
#pragma unroll
    for (int j = 0; j < 2; j++) {
      int p = j * 256 + t;                   // chunk 0..511
      int r = p >> 3, x = p & 7;
      int scol = (x ^ (r & 7)) << 3;
      gload16(&As[p * 8], Ag + (size_t)r * 768 + k0 + scol);
      gload16(&Bs[p * 8], Wg + (size_t)r * 768 + k0 + scol);
    }
    __syncthreads();
#pragma unroll
    for (int kk = 0; kk < 2; kk++) {
      const int kc = kk * 32 + (lane >> 4) * 8;
      bf16x8 af[2], bf[2];
#pragma unroll
      for (int m = 0; m < 2; m++)
        af[m] = *reinterpret_cast<const bf16x8*>(&As[swz64((wr * 32 + m * 16 + (lane & 15)) * 64 + kc)]);
#pragma unroll
      for (int n = 0; n < 2; n++)
        bf[n] = *reinterpret_cast<const bf16x8*>(&Bs[swz64((wc * 32 + n * 16 + (lane & 15)) * 64 + kc)]);
#pragma unroll
      for (int m = 0; m < 2; m++)
#pragma unroll
        for (int n = 0; n < 2; n++)
          acc[m][n] = __builtin_amdgcn_mfma_f32_16x16x32_bf16(af[m], bf[n], acc[m][n], 0, 0, 0);
    }
    __syncthreads();
  }

#pragma unroll
  for (int n = 0; n < 2; n++) {
    const int f = bn * 64 + wc * 32 + n * 16 + (lane & 15);
    const float bv = bias[f];
#pragma unroll
    for (int m = 0; m < 2; m++)
#pragma unroll
      for (int r = 0; r < 4; r++) {
        int i = bm * 64 + wr * 32 + m * 16 + (lane >> 4) * 4 + r;
        out[(size_t)i * 768 + f] = acc[m][n][r] + bv;
      }
  }
}

extern "C" void kernel_launch(void* const* d_in, const int* in_sizes, int n_in,
                              void* d_out, int out_size, void* d_ws, size_t ws_size,
                              hipStream_t stream) {
  const float* inputs = (const float*)d_in[0];
  const int*   mask   = (const int*)d_in[1];
  const float* w_qkv  = (const float*)d_in[2];
  const float* b_qkv  = (const float*)d_in[3];
  const float* w_proj = (const float*)d_in[4];
  const float* b_proj = (const float*)d_in[5];
  float* out = (float*)d_out;

  uint16_t* a_bf  = (uint16_t*)d_ws;                    // 4096*768
  uint16_t* wq_bf = a_bf  + (size_t)4096 * 768;         // 2304*768
  uint16_t* wp_bf = wq_bf + (size_t)2304 * 768;         // 768*768
  uint16_t* q_bf  = wp_bf + (size_t)768 * 768;          // 24*2048*64
  uint16_t* k_bf  = q_bf  + (size_t)24 * 2048 * 64;     // compacted keys
  uint16_t* v_bf  = k_bf  + (size_t)24 * 2048 * 64;     // compacted, [B,H,D,Sc]
  uint16_t* x_bf  = v_bf  + (size_t)24 * 2048 * 64;     // 4096*768
  int*      cpos  = (int*)(x_bf + (size_t)4096 * 768);  // 2*2048 ints
  float*    mbc   = (float*)(cpos + 2 * 2048);          // 2*2048 floats
  int*      ntp   = (int*)(mbc + 2 * 2048);             // 2 ints
  int*      nbp   = ntp + 2;                            // 2 ints

  const int n0 = 4096 * 768 / 4, n1 = 2304 * 768 / 4, n2 = 768 * 768 / 4;
  cvt_all<<<(n0 + n1 + n2 + 255) / 256, 256, 0, stream>>>(
      (const float4*)inputs, (ushort4*)a_bf, n0,
      (const float4*)w_qkv,  (ushort4*)wq_bf, n1,
      (const float4*)w_proj, (ushort4*)wp_bf, n2);
  mask_scan<<<2, 256, 0, stream>>>(mask, cpos, mbc, ntp, nbp);
  pad_fill<<<2 * NHEAD, 256, 0, stream>>>(nbp, k_bf, v_bf);
  qkv_gemm<<<32 * 12, 256, 0, stream>>>(a_bf, wq_bf, b_qkv, cpos, q_bf, k_bf, v_bf);
  attn_kernel<<<24 * 32, 256, 0, stream>>>(q_bf, k_bf, v_bf, mbc, ntp, x_bf);
  proj_gemm<<<64 * 12, 256, 0, stream>>>(x_bf, wp_bf, b_proj, out);
}

// Round 21
// 84.337 us; speedup vs baseline: 1.1732x; 1.1732x over previous
//
#include <hip/hip_runtime.h>
#include <stdint.h>

#define S_LEN 2048
#define EMB   768
#define NHEAD 12
#define HDIM  64

typedef __attribute__((ext_vector_type(8)))  __bf16       bf16x8;
typedef __attribute__((ext_vector_type(4)))  float        f32x4;
typedef __attribute__((ext_vector_type(16))) float        f32x16;
typedef __attribute__((ext_vector_type(2)))  unsigned int u32x2;
typedef __attribute__((ext_vector_type(4)))  unsigned int u32x4;

__device__ __forceinline__ uint16_t f32_to_bf16(float f) {
  uint32_t u = __float_as_uint(f);
  u += 0x7FFFu + ((u >> 16) & 1u);           // round-to-nearest-even
  return (uint16_t)(u >> 16);
}

__device__ __forceinline__ uint32_t cvtpk_bf16(float lo, float hi) {
  uint32_t r;
  asm("v_cvt_pk_bf16_f32 %0, %1, %2" : "=v"(r) : "v"(lo), "v"(hi));
  return r;
}

#if __has_builtin(__builtin_amdgcn_exp2f)
#define EXP2F(x) __builtin_amdgcn_exp2f(x)
#else
#define EXP2F(x) exp2f(x)
#endif

#define ZERO16 {0.f,0.f,0.f,0.f,0.f,0.f,0.f,0.f,0.f,0.f,0.f,0.f,0.f,0.f,0.f,0.f}

// XOR swizzle for [rows][64] bf16 LDS tiles (idx in ushort units).
__device__ __forceinline__ int swz64(int idx) {
  return idx ^ (((idx >> 6) & 7) << 3);
}

// async global->LDS, 16B per lane; dest must be linear (wave base + lane*16)
__device__ __forceinline__ void gload16(uint16_t* lds, const uint16_t* g) {
  __builtin_amdgcn_global_load_lds((const __attribute__((address_space(1))) void*)g,
                                   (__attribute__((address_space(3))) void*)lds, 16, 0, 0);
}

// ---------------- fused fp32 -> bf16 convert (verified r12) ----------------
__global__ __launch_bounds__(256) void cvt_all(const float4* __restrict__ i0, ushort4* __restrict__ o0, int n0,
                                               const float4* __restrict__ i1, ushort4* __restrict__ o1, int n1,
                                               const float4* __restrict__ i2, ushort4* __restrict__ o2, int n2) {
  int gid = blockIdx.x * blockDim.x + threadIdx.x;
  const float4* src;
  ushort4* dst;
  int idx;
  if (gid < n0)           { src = i0; dst = o0; idx = gid; }
  else if (gid < n0 + n1) { src = i1; dst = o1; idx = gid - n0; }
  else if (gid < n0 + n1 + n2) { src = i2; dst = o2; idx = gid - n0 - n1; }
  else return;
  float4 v = src[idx];
  ushort4 o;
  o.x = f32_to_bf16(v.x); o.y = f32_to_bf16(v.y);
  o.z = f32_to_bf16(v.z); o.w = f32_to_bf16(v.w);
  dst[idx] = o;
}

// ---------------- mask scan (parallel, verified r16): cpos, compact bias, tile counts ----------------
__global__ __launch_bounds__(256) void mask_scan(const int* __restrict__ mask,
                                                 int* __restrict__ cpos,
                                                 float* __restrict__ mbc,
                                                 int* __restrict__ ntp,
                                                 int* __restrict__ nbp) {
  const int b    = blockIdx.x;
  const int t    = threadIdx.x;
  const int lane = t & 63;
  const int wvi  = t >> 6;
  __shared__ int wsum[4];
  int m[8], u = 0;
#pragma unroll
  for (int j = 0; j < 8; j++) {
    m[j] = mask[b * S_LEN + t * 8 + j];
    u += (m[j] == 0);
  }
  int x = u;
#pragma unroll
  for (int off = 1; off < 64; off <<= 1) {
    int v = __shfl_up(x, off);
    if (lane >= off) x += v;
  }
  if (lane == 63) wsum[wvi] = x;
  __syncthreads();
  int wbase = 0;
#pragma unroll
  for (int i = 0; i < 4; i++) wbase += (i < wvi) ? wsum[i] : 0;
  const int nb = wsum[0] + wsum[1] + wsum[2] + wsum[3];
  int base = wbase + x - u;                 // exclusive prefix for this thread
#pragma unroll
  for (int j = 0; j < 8; j++) {
    int sc = (m[j] == 0) ? base : -1;
    if (m[j] == 0) base++;
    cpos[b * S_LEN + t * 8 + j] = sc;
    mbc[b * S_LEN + t * 8 + j] = ((t * 8 + j) < nb) ? 0.0f : -1e30f;
  }
  if (t == 0) {
    ntp[b] = ((nb + 63) & ~63) >> 6;
    nbp[b] = nb;
  }
}

// ---------------- pad fill (verified r16): zero pad rows of K / pad cols of V^T ----------------
__global__ __launch_bounds__(256) void pad_fill(const int* __restrict__ nbp,
                                                uint16_t* __restrict__ kb,
                                                uint16_t* __restrict__ vb) {
  const int b = blockIdx.x / NHEAD, h = blockIdx.x % NHEAD;
  const int t = threadIdx.x;
  const int nb = nbp[b];
  const int padN = (nb + 63) & ~63;
  const int npad = padN - nb;
  for (int idx = t; idx < npad * HDIM; idx += 256) {
    int row = idx >> 6, d = idx & (HDIM - 1);
    kb[(((size_t)b * NHEAD + h) * S_LEN + nb + row) * HDIM + d] = 0;
    vb[(((size_t)b * NHEAD + h) * HDIM + d) * S_LEN + nb + row] = 0;
  }
}

// ---------------- QKV GEMM: BM=128, BN=96, 768 blocks (3/CU) ----------------
// Dual-term optimum: staged bytes 340 -> 258MB (A re-read 24x not 36x) at CONSTANT
// 3-blocks/CU occupancy (r20's G=3 cut bytes but starved the grid at 1.5/CU).
// 24 N-tiles = 8 per Q/K/V -> cQ = bn/8 block-uniform, verified epilogue applies.
__global__ __launch_bounds__(256) void qkv_gemm(const uint16_t* __restrict__ A,
                                                const uint16_t* __restrict__ W,
                                                const float* __restrict__ bias,
                                                const int* __restrict__ cpos,
                                                uint16_t* __restrict__ qb,
                                                uint16_t* __restrict__ kb,
                                                uint16_t* __restrict__ vb) {
  __shared__ __align__(16) uint16_t As[128 * 64];   // 16KB
  __shared__ __align__(16) uint16_t Bs[96 * 64];    // 12KB
  const int t    = threadIdx.x;
  const int lane = t & 63;
  const int wv   = t >> 6;
  const int wr   = wv >> 1, wc = wv & 1;
  // bijective XCD swizzle, bn-fast: 768 = 8 * 96, 96 = 4 bm * 24 bn
  const int wg   = (blockIdx.x & 7) * 96 + (blockIdx.x >> 3);
  const int bm   = wg / 24;                  // 32 M tiles (128 rows); 4 per XCD
  const int bn   = wg % 24;                  // 24 N tiles (96 cols); all per XCD
  const int cQ   = bn >> 3;                  // 0=Q, 1=K, 2=V (block-uniform)

  const uint16_t* Ag = A + (size_t)bm * 128 * 768;
  const uint16_t* Wg = W + (size_t)bn * 96 * 768;

  f32x4 zf = {0.f, 0.f, 0.f, 0.f};
  f32x4 acc[4][3];
#pragma unroll
  for (int m = 0; m < 4; m++)
#pragma unroll
    for (int n = 0; n < 3; n++) acc[m][n] = zf;

  for (int k0 = 0; k0 < 768; k0 += 64) {
#pragma unroll
    for (int j = 0; j < 4; j++) {            // A tile: 1024 chunks
      int p = j * 256 + t;
      int r = p >> 3, x = p & 7;
      int scol = (x ^ (r & 7)) << 3;
      gload16(&As[p * 8], Ag + (size_t)r * 768 + k0 + scol);
    }
#pragma unroll
    for (int j = 0; j < 3; j++) {            // B tile: 96 rows = 768 chunks
      int p = j * 256 + t;
      int r = p >> 3, x = p & 7;
      int scol = (x ^ (r & 7)) << 3;
      gload16(&Bs[p * 8], Wg + (size_t)r * 768 + k0 + scol);
    }
    __syncthreads();
#pragma unroll
    for (int kk = 0; kk < 2; kk++) {
      const int kc = kk * 32 + (lane >> 4) * 8;
      bf16x8 af[4], bf[3];
#pragma unroll
      for (int m = 0; m < 4; m++)
        af[m] = *reinterpret_cast<const bf16x8*>(&As[swz64((wr * 64 + m * 16 + (lane & 15)) * 64 + kc)]);
#pragma unroll
      for (int n = 0; n < 3; n++)
        bf[n] = *reinterpret_cast<const bf16x8*>(&Bs[swz64((wc * 48 + n * 16 + (lane & 15)) * 64 + kc)]);
#pragma unroll
      for (int m = 0; m < 4; m++)
#pragma unroll
        for (int n = 0; n < 3; n++)
          acc[m][n] = __builtin_amdgcn_mfma_f32_16x16x32_bf16(af[m], bf[n], acc[m][n], 0, 0, 0);
    }
    __syncthreads();
  }

  int scv[4][4];
  if (cQ != 0) {
#pragma unroll
    for (int m = 0; m < 4; m++)
#pragma unroll
      for (int r = 0; r < 4; r++) {
        int i = bm * 128 + wr * 64 + m * 16 + (lane >> 4) * 4 + r;
        scv[m][r] = cpos[(i >> 11) * S_LEN + (i & 2047)];
      }
  }
#pragma unroll
  for (int n = 0; n < 3; n++) {
    const int f   = bn * 96 + wc * 48 + n * 16 + (lane & 15);
    const float bv = bias[f];
    const int rem = f - cQ * 768;
    const int h   = rem >> 6, d = rem & 63;
    const float scl = (cQ == 0) ? 0.125f * 1.44269504f : 1.0f;  // SCALE*log2e folded into Q
#pragma unroll
    for (int m = 0; m < 4; m++) {
#pragma unroll
      for (int r = 0; r < 4; r++) {
        int i = bm * 128 + wr * 64 + m * 16 + (lane >> 4) * 4 + r;
        int b = i >> 11, s = i & 2047;
        uint16_t val = f32_to_bf16((acc[m][n][r] + bv) * scl);
        if (cQ == 0) {
          qb[(((size_t)b * NHEAD + h) * S_LEN + s) * HDIM + d] = val;
        } else {
          int sc = scv[m][r];
          if (sc >= 0) {
            if (cQ == 1)
              kb[(((size_t)b * NHEAD + h) * S_LEN + sc) * HDIM + d] = val;
            else
              vb[(((size_t)b * NHEAD + h) * HDIM + d) * S_LEN + sc] = val;  // V transposed
          }
        }
      }
    }
  }
}

// ---------------- Flash attention (verified r16): compacted keys, tail-only bias ----------------
__global__ __launch_bounds__(256, 3) void attn_kernel(const uint16_t* __restrict__ Q,   // [BH][S][D], pre-scaled
                                                      const uint16_t* __restrict__ Kb,  // [BH][Sc][D] compacted
                                                      const uint16_t* __restrict__ Vb,  // [BH][D][Sc] compacted
                                                      const float* __restrict__ mbc,    // [B][S] compact bias
                                                      const int* __restrict__ ntp,      // [B] tile count
                                                      uint16_t* __restrict__ X) {       // [B][S][E] bf16
  __shared__ __align__(16) uint16_t Kd[2][64 * 64];
  __shared__ __align__(16) uint16_t Vd[2][64 * 64];   // [d][key]
  __shared__ __align__(16) float    mb_s[S_LEN];
  __shared__ float Lc[2][32];

  const int t    = threadIdx.x;
  const int lane = t & 63;
  const int hl   = lane >> 5;                   // lane half
  const int q31  = lane & 31;
  const int wv   = t >> 6;
  const int qg   = wv & 1;                      // q-group
  const int kh   = wv >> 1;                     // key-half
  // bijective XCD swizzle: 768 = 8 * 96; each XCD gets 3 whole heads (L2-fit K/V)
  const int wg   = (blockIdx.x & 7) * 96 + (blockIdx.x >> 3);
  const int qblk = wg & 31;
  const int bh   = wg >> 5;
  const int b    = bh / NHEAD, hd = bh % NHEAD;

  const uint16_t* Qh = Q  + (size_t)bh * S_LEN * HDIM;
  const uint16_t* Kh = Kb + (size_t)bh * S_LEN * HDIM;
  const uint16_t* Vh = Vb + (size_t)bh * HDIM * S_LEN;
  const int q0 = qblk * 64 + qg * 32;
  const int nt = ntp[b];

  // compact bias preload (8 keys/thread, coalesced float4)
  {
    float4 f0 = *reinterpret_cast<const float4*>(&mbc[b * S_LEN + t * 8]);
    float4 f1 = *reinterpret_cast<const float4*>(&mbc[b * S_LEN + t * 8 + 4]);
    *reinterpret_cast<float4*>(&mb_s[t * 8])     = f0;
    *reinterpret_cast<float4*>(&mb_s[t * 8 + 4]) = f1;
  }

  // Q as B-fragments: col=q31, k=d=16s+8hl+j
  bf16x8 qf[4];
#pragma unroll
  for (int s = 0; s < 4; s++)
    qf[s] = *reinterpret_cast<const bf16x8*>(Qh + (size_t)(q0 + q31) * HDIM + 16 * s + 8 * hl);

  f32x16 oacc[2] = {ZERO16, ZERO16};
  float lsum = 0.f;

  const uint16_t* kga[2]; const uint16_t* vga[2]; int lof[2];
#pragma unroll
  for (int j = 0; j < 2; j++) {
    int p = j * 256 + t, r = p >> 3, x = p & 7;
    int scol = (x ^ (r & 7)) << 3;
    kga[j] = Kh + (size_t)r * HDIM + scol;
    vga[j] = Vh + (size_t)r * S_LEN + scol;
    lof[j] = p * 8;
  }
  auto stage = [&](int nb2, int it2) {   // 4 vmem instructions per thread
#pragma unroll
    for (int j = 0; j < 2; j++) {
      gload16(&Kd[nb2][lof[j]], kga[j] + it2 * 64 * HDIM);
      gload16(&Vd[nb2][lof[j]], vga[j] + it2 * 64);
    }
  };

  stage(0, 0);
  __syncthreads();                       // prologue: full drain, bias + buf0 ready

#pragma unroll 2
  for (int it = 0; it < nt; ++it) {
    const int cur = it & 1;
    __builtin_amdgcn_s_barrier();        // A: all waves done compute(it-1) -> buf cur^1 free
    __builtin_amdgcn_sched_barrier(0);
    if (it + 1 < nt) {
      stage(cur ^ 1, it + 1);            // next-tile loads: stay in flight across B
      asm volatile("s_waitcnt vmcnt(4)" ::: "memory");   // my tile-it loads done
    } else {
      asm volatile("s_waitcnt vmcnt(0)" ::: "memory");
    }
    __builtin_amdgcn_s_barrier();        // B: buf cur staged block-wide
    __builtin_amdgcn_sched_barrier(0);

    // QK^T (swapped): scc[reg] = S[key_loc=(reg&3)+8*(reg>>2)+4*hl][q31]
    f32x16 scc = ZERO16;
    __builtin_amdgcn_s_setprio(1);
#pragma unroll
    for (int s = 0; s < 4; s++) {
      bf16x8 kf = *reinterpret_cast<const bf16x8*>(&Kd[cur][swz64((kh * 32 + q31) * 64 + 16 * s + 8 * hl)]);
      scc = __builtin_amdgcn_mfma_f32_32x32x16_bf16(kf, qf[s], scc, 0, 0, 0);
    }
    __builtin_amdgcn_s_setprio(0);

    // exp2 + per-lane sum; bias only on the tail tile (compacted keys have bias 0)
    uint32_t w[4][2];
    if (it == nt - 1) {
#pragma unroll
      for (int s2 = 0; s2 < 4; s2++) {
        f32x4 mbv = *reinterpret_cast<const f32x4*>(&mb_s[it * 64 + kh * 32 + s2 * 8 + hl * 4]);
        float p0 = EXP2F(scc[4 * s2 + 0] + mbv[0]);
        float p1 = EXP2F(scc[4 * s2 + 1] + mbv[1]);
        float p2 = EXP2F(scc[4 * s2 + 2] + mbv[2]);
        float p3 = EXP2F(scc[4 * s2 + 3] + mbv[3]);
        lsum += (p0 + p1) + (p2 + p3);
        w[s2][0] = cvtpk_bf16(p0, p1);
        w[s2][1] = cvtpk_bf16(p2, p3);
      }
    } else {
#pragma unroll
      for (int s2 = 0; s2 < 4; s2++) {
        float p0 = EXP2F(scc[4 * s2 + 0]);
        float p1 = EXP2F(scc[4 * s2 + 1]);
        float p2 = EXP2F(scc[4 * s2 + 2]);
        float p3 = EXP2F(scc[4 * s2 + 3]);
        lsum += (p0 + p1) + (p2 + p3);
        w[s2][0] = cvtpk_bf16(p0, p1);
        w[s2][1] = cvtpk_bf16(p2, p3);
      }
    }

    // redistribute P into PV B-fragments: pb[ks][j] = P[16ks+8hl+j][q31]
    bf16x8 pb[2];
#pragma unroll
    for (int ks = 0; ks < 2; ks++) {
      u32x2 r0 = __builtin_amdgcn_permlane32_swap(w[2 * ks][0], w[2 * ks + 1][0], false, false);
      u32x2 r1 = __builtin_amdgcn_permlane32_swap(w[2 * ks][1], w[2 * ks + 1][1], false, false);
      u32x4 uu;
      uu.x = r0.x; uu.y = r1.x; uu.z = r0.y; uu.w = r1.y;
      pb[ks] = __builtin_bit_cast(bf16x8, uu);
    }

    // PV (swapped): O^T[d][q] += V^T[d][k] * P[k][q]
    __builtin_amdgcn_s_setprio(1);
#pragma unroll
    for (int mt = 0; mt < 2; mt++)
#pragma unroll
      for (int ks = 0; ks < 2; ks++) {
        bf16x8 vf = *reinterpret_cast<const bf16x8*>(&Vd[cur][swz64((mt * 32 + q31) * 64 + kh * 32 + ks * 16 + hl * 8)]);
        oacc[mt] = __builtin_amdgcn_mfma_f32_32x32x16_bf16(vf, pb[ks], oacc[mt], 0, 0, 0);
      }
    __builtin_amdgcn_s_setprio(0);
  }

  // per-wave row sum for column q31
  lsum += __shfl_xor(lsum, 32);

  __syncthreads();   // nt may be odd: all waves done reading buf0 before Oc alias write

  // combine key-half partials: kh=1 writes O^T and l, kh=0 finishes
  float* Oc = qg ? (float*)&Vd[0][0] : (float*)&Kd[0][0];   // [64 d][32 q]
  if (kh == 1) {
#pragma unroll
    for (int mt = 0; mt < 2; mt++)
#pragma unroll
      for (int e = 0; e < 16; e++) {
        int d = mt * 32 + (e & 3) + (e >> 2) * 8 + hl * 4;
        Oc[d * 32 + q31] = oacc[mt][e];
      }
    if (hl == 0) Lc[qg][q31] = lsum;
  }
  __syncthreads();
  if (kh == 0) {
    float linv = 1.0f / (lsum + Lc[qg][q31]);
    uint16_t* Xr = X + ((size_t)b * S_LEN + q0 + q31) * EMB + hd * HDIM;
#pragma unroll
    for (int mt = 0; mt < 2; mt++)
#pragma unroll
      for (int s2 = 0; s2 < 4; s2++) {
        int d0 = mt * 32 + s2 * 8 + hl * 4;
        float v0 = (oacc[mt][4 * s2 + 0] + Oc[(d0 + 0) * 32 + q31]) * linv;
        float v1 = (oacc[mt][4 * s2 + 1] + Oc[(d0 + 1) * 32 + q31]) * linv;
        float v2 = (oacc[mt][4 * s2 + 2] + Oc[(d0 + 2) * 32 + q31]) * linv;
        float v3 = (oacc[mt][4 * s2 + 3] + Oc[(d0 + 3) * 32 + q31]) * linv;
        uint2 ww;
        ww.x = cvtpk_bf16(v0, v1);
        ww.y = cvtpk_bf16(v2, v3);
        *reinterpret_cast<uint2*>(Xr + d0) = ww;
      }
  }
}

// ---------------- Proj GEMM (verified r17): 64x64 tiles, bn-fast XCD decode ----------------
__global__ __launch_bounds__(256) void proj_gemm(const uint16_t* __restrict__ A,
                                                 const uint16_t* __restrict__ W,
                                                 const float* __restrict__ bias,
                                                 float* __restrict__ out) {
  __shared__ __align__(16) uint16_t As[64 * 64];
  __shared__ __align__(16) uint16_t Bs[64 * 64];
  const int t    = threadIdx.x;
  const int lane = t & 63;
  const int wv   = t >> 6;
  const int wr   = wv >> 1, wc = wv & 1;
  // bijective XCD swizzle, bn-fast: 768 = 8 * 96, 96 = 8 bm * 12 bn
  const int wg   = (blockIdx.x & 7) * 96 + (blockIdx.x >> 3);
  const int bm   = wg / 12;                  // 64 M tiles; 8 per XCD
  const int bn   = wg % 12;                  // 12 N tiles; all per XCD

  const uint16_t* Ag = A + (size_t)bm * 64 * 768;
  const uint16_t* Wg = W + (size_t)bn * 64 * 768;

  f32x4 zf = {0.f, 0.f, 0.f, 0.f};
  f32x4 acc[2][2];
#pragma unroll
  for (int m = 0; m < 2; m++)
#pragma unroll
    for (int n = 0; n < 2; n++) acc[m][n] = zf;

  for (int k0 = 0; k0 < 768; k0 += 64) {
#pragma unroll
    for (int j = 0; j < 2; j++) {
      int p = j * 256 + t;                   // chunk 0..511
      int r = p >> 3, x = p & 7;
      int scol = (x ^ (r & 7)) << 3;
      gload16(&As[p * 8], Ag + (size_t)r * 768 + k0 + scol);
      gload16(&Bs[p * 8], Wg + (size_t)r * 768 + k0 + scol);
    }
    __syncthreads();
#pragma unroll
    for (int kk = 0; kk < 2; kk++) {
      const int kc = kk * 32 + (lane >> 4) * 8;
      bf16x8 af[2], bf[2];
#pragma unroll
      for (int m = 0; m < 2; m++)
        af[m] = *reinterpret_cast<const bf16x8*>(&As[swz64((wr * 32 + m * 16 + (lane & 15)) * 64 + kc)]);
#pragma unroll
      for (int n = 0; n < 2; n++)
        bf[n] = *reinterpret_cast<const bf16x8*>(&Bs[swz64((wc * 32 + n * 16 + (lane & 15)) * 64 + kc)]);
#pragma unroll
      for (int m = 0; m < 2; m++)
#pragma unroll
        for (int n = 0; n < 2; n++)
          acc[m][n] = __builtin_amdgcn_mfma_f32_16x16x32_bf16(af[m], bf[n], acc[m][n], 0, 0, 0);
    }
    __syncthreads();
  }

#pragma unroll
  for (int n = 0; n < 2; n++) {
    const int f = bn * 64 + wc * 32 + n * 16 + (lane & 15);
    const float bv = bias[f];
#pragma unroll
    for (int m = 0; m < 2; m++)
#pragma unroll
      for (int r = 0; r < 4; r++) {
        int i = bm * 64 + wr * 32 + m * 16 + (lane >> 4) * 4 + r;
        out[(size_t)i * 768 + f] = acc[m][n][r] + bv;
      }
  }
}

extern "C" void kernel_launch(void* const* d_in, const int* in_sizes, int n_in,
                              void* d_out, int out_size, void* d_ws, size_t ws_size,
                              hipStream_t stream) {
  const float* inputs = (const float*)d_in[0];
  const int*   mask   = (const int*)d_in[1];
  const float* w_qkv  = (const float*)d_in[2];
  const float* b_qkv  = (const float*)d_in[3];
  const float* w_proj = (const float*)d_in[4];
  const float* b_proj = (const float*)d_in[5];
  float* out = (float*)d_out;

  uint16_t* a_bf  = (uint16_t*)d_ws;                    // 4096*768
  uint16_t* wq_bf = a_bf  + (size_t)4096 * 768;         // 2304*768
  uint16_t* wp_bf = wq_bf + (size_t)2304 * 768;         // 768*768
  uint16_t* q_bf  = wp_bf + (size_t)768 * 768;          // 24*2048*64
  uint16_t* k_bf  = q_bf  + (size_t)24 * 2048 * 64;     // compacted keys
  uint16_t* v_bf  = k_bf  + (size_t)24 * 2048 * 64;     // compacted, [B,H,D,Sc]
  uint16_t* x_bf  = v_bf  + (size_t)24 * 2048 * 64;     // 4096*768
  int*      cpos  = (int*)(x_bf + (size_t)4096 * 768);  // 2*2048 ints
  float*    mbc   = (float*)(cpos + 2 * 2048);          // 2*2048 floats
  int*      ntp   = (int*)(mbc + 2 * 2048);             // 2 ints
  int*      nbp   = ntp + 2;                            // 2 ints

  const int n0 = 4096 * 768 / 4, n1 = 2304 * 768 / 4, n2 = 768 * 768 / 4;
  cvt_all<<<(n0 + n1 + n2 + 255) / 256, 256, 0, stream>>>(
      (const float4*)inputs, (ushort4*)a_bf, n0,
      (const float4*)w_qkv,  (ushort4*)wq_bf, n1,
      (const float4*)w_proj, (ushort4*)wp_bf, n2);
  mask_scan<<<2, 256, 0, stream>>>(mask, cpos, mbc, ntp, nbp);
  pad_fill<<<2 * NHEAD, 256, 0, stream>>>(nbp, k_bf, v_bf);
  qkv_gemm<<<32 * 24, 256, 0, stream>>>(a_bf, wq_bf, b_qkv, cpos, q_bf, k_bf, v_bf);
  attn_kernel<<<24 * 32, 256, 0, stream>>>(q_bf, k_bf, v_bf, mbc, ntp, x_bf);
  proj_gemm<<<64 * 12, 256, 0, stream>>>(x_bf, wp_bf, b_proj, out);
}

// Round 22
// 80.182 us; speedup vs baseline: 1.2340x; 1.0518x over previous
//
#include <hip/hip_runtime.h>
#include <stdint.h>

#define S_LEN 2048
#define EMB   768
#define NHEAD 12
#define HDIM  64

typedef __attribute__((ext_vector_type(8)))  __bf16       bf16x8;
typedef __attribute__((ext_vector_type(4)))  float        f32x4;
typedef __attribute__((ext_vector_type(16))) float        f32x16;
typedef __attribute__((ext_vector_type(2)))  unsigned int u32x2;
typedef __attribute__((ext_vector_type(4)))  unsigned int u32x4;

__device__ __forceinline__ uint16_t f32_to_bf16(float f) {
  uint32_t u = __float_as_uint(f);
  u += 0x7FFFu + ((u >> 16) & 1u);           // round-to-nearest-even
  return (uint16_t)(u >> 16);
}

__device__ __forceinline__ uint32_t cvtpk_bf16(float lo, float hi) {
  uint32_t r;
  asm("v_cvt_pk_bf16_f32 %0, %1, %2" : "=v"(r) : "v"(lo), "v"(hi));
  return r;
}

#if __has_builtin(__builtin_amdgcn_exp2f)
#define EXP2F(x) __builtin_amdgcn_exp2f(x)
#else
#define EXP2F(x) exp2f(x)
#endif

#define ZERO16 {0.f,0.f,0.f,0.f,0.f,0.f,0.f,0.f,0.f,0.f,0.f,0.f,0.f,0.f,0.f,0.f}

// XOR swizzle for [rows][64] bf16 LDS tiles (idx in ushort units).
__device__ __forceinline__ int swz64(int idx) {
  return idx ^ (((idx >> 6) & 7) << 3);
}

// XOR swizzle for [rows][128] bf16 LDS tiles (idx in ushort units).
__device__ __forceinline__ int swz128(int idx) {
  return idx ^ (((idx >> 7) & 7) << 3);
}

// async global->LDS, 16B per lane; dest must be linear (wave base + lane*16)
__device__ __forceinline__ void gload16(uint16_t* lds, const uint16_t* g) {
  __builtin_amdgcn_global_load_lds((const __attribute__((address_space(1))) void*)g,
                                   (__attribute__((address_space(3))) void*)lds, 16, 0, 0);
}

// ---------------- fused fp32->bf16 convert + mask scan (tail blocks) ----------------
// Blocks [0, cvtBlocks): elementwise convert (verified r12 body).
// Blocks [cvtBlocks, cvtBlocks+2): per-batch mask scan (verified r16 body) —
// independent work (reads only mask), block-uniform branch so syncthreads is legal.
__global__ __launch_bounds__(256) void cvt_all(const float4* __restrict__ i0, ushort4* __restrict__ o0, int n0,
                                               const float4* __restrict__ i1, ushort4* __restrict__ o1, int n1,
                                               const float4* __restrict__ i2, ushort4* __restrict__ o2, int n2,
                                               const int* __restrict__ mask,
                                               int* __restrict__ cpos, float* __restrict__ mbc,
                                               int* __restrict__ ntp, int* __restrict__ nbp,
                                               int cvtBlocks) {
  if ((int)blockIdx.x >= cvtBlocks) {
    const int b    = blockIdx.x - cvtBlocks;
    const int t    = threadIdx.x;
    const int lane = t & 63;
    const int wvi  = t >> 6;
    __shared__ int wsum[4];
    int m[8], u = 0;
#pragma unroll
    for (int j = 0; j < 8; j++) {
      m[j] = mask[b * S_LEN + t * 8 + j];
      u += (m[j] == 0);
    }
    int x = u;
#pragma unroll
    for (int off = 1; off < 64; off <<= 1) {
      int v = __shfl_up(x, off);
      if (lane >= off) x += v;
    }
    if (lane == 63) wsum[wvi] = x;
    __syncthreads();
    int wbase = 0;
#pragma unroll
    for (int i = 0; i < 4; i++) wbase += (i < wvi) ? wsum[i] : 0;
    const int nb = wsum[0] + wsum[1] + wsum[2] + wsum[3];
    int base = wbase + x - u;               // exclusive prefix for this thread
#pragma unroll
    for (int j = 0; j < 8; j++) {
      int sc = (m[j] == 0) ? base : -1;
      if (m[j] == 0) base++;
      cpos[b * S_LEN + t * 8 + j] = sc;
      mbc[b * S_LEN + t * 8 + j] = ((t * 8 + j) < nb) ? 0.0f : -1e30f;
    }
    if (t == 0) {
      ntp[b] = ((nb + 63) & ~63) >> 6;
      nbp[b] = nb;
    }
    return;
  }
  int gid = blockIdx.x * blockDim.x + threadIdx.x;
  const float4* src;
  ushort4* dst;
  int idx;
  if (gid < n0)           { src = i0; dst = o0; idx = gid; }
  else if (gid < n0 + n1) { src = i1; dst = o1; idx = gid - n0; }
  else if (gid < n0 + n1 + n2) { src = i2; dst = o2; idx = gid - n0 - n1; }
  else return;
  float4 v = src[idx];
  ushort4 o;
  o.x = f32_to_bf16(v.x); o.y = f32_to_bf16(v.y);
  o.z = f32_to_bf16(v.z); o.w = f32_to_bf16(v.w);
  dst[idx] = o;
}

// ---------------- pad fill (verified r16): zero pad rows of K / pad cols of V^T ----------------
__global__ __launch_bounds__(256) void pad_fill(const int* __restrict__ nbp,
                                                uint16_t* __restrict__ kb,
                                                uint16_t* __restrict__ vb) {
  const int b = blockIdx.x / NHEAD, h = blockIdx.x % NHEAD;
  const int t = threadIdx.x;
  const int nb = nbp[b];
  const int padN = (nb + 63) & ~63;
  const int npad = padN - nb;
  for (int idx = t; idx < npad * HDIM; idx += 256) {
    int row = idx >> 6, d = idx & (HDIM - 1);
    kb[(((size_t)b * NHEAD + h) * S_LEN + nb + row) * HDIM + d] = 0;
    vb[(((size_t)b * NHEAD + h) * HDIM + d) * S_LEN + nb + row] = 0;
  }
}

// ---------------- QKV GEMM (verified r18): BM=128, BN=64, BK=128, 1152 blocks ----------------
__global__ __launch_bounds__(256) void qkv_gemm(const uint16_t* __restrict__ A,
                                                const uint16_t* __restrict__ W,
                                                const float* __restrict__ bias,
                                                const int* __restrict__ cpos,
                                                uint16_t* __restrict__ qb,
                                                uint16_t* __restrict__ kb,
                                                uint16_t* __restrict__ vb) {
  __shared__ __align__(16) uint16_t As[128 * 128];   // 32KB
  __shared__ __align__(16) uint16_t Bs[64 * 128];    // 16KB
  const int t    = threadIdx.x;
  const int lane = t & 63;
  const int wv   = t >> 6;
  const int wr   = wv >> 1, wc = wv & 1;
  // bijective XCD swizzle, bn-fast: 1152 = 8 * 144, 144 = 4 bm * 36 bn
  const int wg   = (blockIdx.x & 7) * 144 + (blockIdx.x >> 3);
  const int bm   = wg / 36;                  // 32 M tiles (128 rows)
  const int bn   = wg % 36;                  // 36 N tiles (64 cols)

  const uint16_t* Ag = A + (size_t)bm * 128 * 768;
  const uint16_t* Wg = W + (size_t)bn * 64 * 768;

  f32x4 zf = {0.f, 0.f, 0.f, 0.f};
  f32x4 acc[4][2];
#pragma unroll
  for (int m = 0; m < 4; m++)
#pragma unroll
    for (int n = 0; n < 2; n++) acc[m][n] = zf;

  for (int k0 = 0; k0 < 768; k0 += 128) {
#pragma unroll
    for (int j = 0; j < 8; j++) {            // A tile: 2048 chunks
      int p = j * 256 + t;
      int r = p >> 4, x = p & 15;
      int scol = (((x & 8) | ((x & 7) ^ (r & 7)))) << 3;
      gload16(&As[p * 8], Ag + (size_t)r * 768 + k0 + scol);
    }
#pragma unroll
    for (int j = 0; j < 4; j++) {            // B tile: 1024 chunks
      int p = j * 256 + t;
      int r = p >> 4, x = p & 15;
      int scol = (((x & 8) | ((x & 7) ^ (r & 7)))) << 3;
      gload16(&Bs[p * 8], Wg + (size_t)r * 768 + k0 + scol);
    }
    __syncthreads();
#pragma unroll
    for (int kk = 0; kk < 4; kk++) {
      const int kc = kk * 32 + (lane >> 4) * 8;
      bf16x8 af[4], bf[2];
#pragma unroll
      for (int m = 0; m < 4; m++)
        af[m] = *reinterpret_cast<const bf16x8*>(&As[swz128((wr * 64 + m * 16 + (lane & 15)) * 128 + kc)]);
#pragma unroll
      for (int n = 0; n < 2; n++)
        bf[n] = *reinterpret_cast<const bf16x8*>(&Bs[swz128((wc * 32 + n * 16 + (lane & 15)) * 128 + kc)]);
#pragma unroll
      for (int m = 0; m < 4; m++)
#pragma unroll
        for (int n = 0; n < 2; n++)
          acc[m][n] = __builtin_amdgcn_mfma_f32_16x16x32_bf16(af[m], bf[n], acc[m][n], 0, 0, 0);
    }
    __syncthreads();
  }

  const int cQ = bn / 12;                    // 0=Q, 1=K, 2=V (block-uniform)
  int scv[4][4];
  if (cQ != 0) {
#pragma unroll
    for (int m = 0; m < 4; m++)
#pragma unroll
      for (int r = 0; r < 4; r++) {
        int i = bm * 128 + wr * 64 + m * 16 + (lane >> 4) * 4 + r;
        scv[m][r] = cpos[(i >> 11) * S_LEN + (i & 2047)];
      }
  }
#pragma unroll
  for (int n = 0; n < 2; n++) {
    const int f   = bn * 64 + wc * 32 + n * 16 + (lane & 15);
    const float bv = bias[f];
    const int rem = f - cQ * 768;
    const int h   = rem >> 6, d = rem & 63;
    const float scl = (cQ == 0) ? 0.125f * 1.44269504f : 1.0f;  // SCALE*log2e folded into Q
#pragma unroll
    for (int m = 0; m < 4; m++) {
#pragma unroll
      for (int r = 0; r < 4; r++) {
        int i = bm * 128 + wr * 64 + m * 16 + (lane >> 4) * 4 + r;
        int b = i >> 11, s = i & 2047;
        uint16_t val = f32_to_bf16((acc[m][n][r] + bv) * scl);
        if (cQ == 0) {
          qb[(((size_t)b * NHEAD + h) * S_LEN + s) * HDIM + d] = val;
        } else {
          int sc = scv[m][r];
          if (sc >= 0) {
            if (cQ == 1)
              kb[(((size_t)b * NHEAD + h) * S_LEN + sc) * HDIM + d] = val;
            else
              vb[(((size_t)b * NHEAD + h) * HDIM + d) * S_LEN + sc] = val;  // V transposed
          }
        }
      }
    }
  }
}

// ---------------- Flash attention (verified r16): compacted keys, tail-only bias ----------------
__global__ __launch_bounds__(256, 3) void attn_kernel(const uint16_t* __restrict__ Q,   // [BH][S][D], pre-scaled
                                                      const uint16_t* __restrict__ Kb,  // [BH][Sc][D] compacted
                                                      const uint16_t* __restrict__ Vb,  // [BH][D][Sc] compacted
                                                      const float* __restrict__ mbc,    // [B][S] compact bias
                                                      const int* __restrict__ ntp,      // [B] tile count
                                                      uint16_t* __restrict__ X) {       // [B][S][E] bf16
  __shared__ __align__(16) uint16_t Kd[2][64 * 64];
  __shared__ __align__(16) uint16_t Vd[2][64 * 64];   // [d][key]
  __shared__ __align__(16) float    mb_s[S_LEN];
  __shared__ float Lc[2][32];

  const int t    = threadIdx.x;
  const int lane = t & 63;
  const int hl   = lane >> 5;                   // lane half
  const int q31  = lane & 31;
  const int wv   = t >> 6;
  const int qg   = wv & 1;                      // q-group
  const int kh   = wv >> 1;                     // key-half
  // bijective XCD swizzle: 768 = 8 * 96; each XCD gets 3 whole heads (L2-fit K/V)
  const int wg   = (blockIdx.x & 7) * 96 + (blockIdx.x >> 3);
  const int qblk = wg & 31;
  const int bh   = wg >> 5;
  const int b    = bh / NHEAD, hd = bh % NHEAD;

  const uint16_t* Qh = Q  + (size_t)bh * S_LEN * HDIM;
  const uint16_t* Kh = Kb + (size_t)bh * S_LEN * HDIM;
  const uint16_t* Vh = Vb + (size_t)bh * HDIM * S_LEN;
  const int q0 = qblk * 64 + qg * 32;
  const int nt = ntp[b];

  // compact bias preload (8 keys/thread, coalesced float4)
  {
    float4 f0 = *reinterpret_cast<const float4*>(&mbc[b * S_LEN + t * 8]);
    float4 f1 = *reinterpret_cast<const float4*>(&mbc[b * S_LEN + t * 8 + 4]);
    *reinterpret_cast<float4*>(&mb_s[t * 8])     = f0;
    *reinterpret_cast<float4*>(&mb_s[t * 8 + 4]) = f1;
  }

  // Q as B-fragments: col=q31, k=d=16s+8hl+j
  bf16x8 qf[4];
#pragma unroll
  for (int s = 0; s < 4; s++)
    qf[s] = *reinterpret_cast<const bf16x8*>(Qh + (size_t)(q0 + q31) * HDIM + 16 * s + 8 * hl);

  f32x16 oacc[2] = {ZERO16, ZERO16};
  float lsum = 0.f;

  const uint16_t* kga[2]; const uint16_t* vga[2]; int lof[2];
#pragma unroll
  for (int j = 0; j < 2; j++) {
    int p = j * 256 + t, r = p >> 3, x = p & 7;
    int scol = (x ^ (r & 7)) << 3;
    kga[j] = Kh + (size_t)r * HDIM + scol;
    vga[j] = Vh + (size_t)r * S_LEN + scol;
    lof[j] = p * 8;
  }
  auto stage = [&](int nb2, int it2) {   // 4 vmem instructions per thread
#pragma unroll
    for (int j = 0; j < 2; j++) {
      gload16(&Kd[nb2][lof[j]], kga[j] + it2 * 64 * HDIM);
      gload16(&Vd[nb2][lof[j]], vga[j] + it2 * 64);
    }
  };

  stage(0, 0);
  __syncthreads();                       // prologue: full drain, bias + buf0 ready

#pragma unroll 2
  for (int it = 0; it < nt; ++it) {
    const int cur = it & 1;
    __builtin_amdgcn_s_barrier();        // A: all waves done compute(it-1) -> buf cur^1 free
    __builtin_amdgcn_sched_barrier(0);
    if (it + 1 < nt) {
      stage(cur ^ 1, it + 1);            // next-tile loads: stay in flight across B
      asm volatile("s_waitcnt vmcnt(4)" ::: "memory");   // my tile-it loads done
    } else {
      asm volatile("s_waitcnt vmcnt(0)" ::: "memory");
    }
    __builtin_amdgcn_s_barrier();        // B: buf cur staged block-wide
    __builtin_amdgcn_sched_barrier(0);

    // QK^T (swapped): scc[reg] = S[key_loc=(reg&3)+8*(reg>>2)+4*hl][q31]
    f32x16 scc = ZERO16;
    __builtin_amdgcn_s_setprio(1);
#pragma unroll
    for (int s = 0; s < 4; s++) {
      bf16x8 kf = *reinterpret_cast<const bf16x8*>(&Kd[cur][swz64((kh * 32 + q31) * 64 + 16 * s + 8 * hl)]);
      scc = __builtin_amdgcn_mfma_f32_32x32x16_bf16(kf, qf[s], scc, 0, 0, 0);
    }
    __builtin_amdgcn_s_setprio(0);

    // exp2 + per-lane sum; bias only on the tail tile (compacted keys have bias 0)
    uint32_t w[4][2];
    if (it == nt - 1) {
#pragma unroll
      for (int s2 = 0; s2 < 4; s2++) {
        f32x4 mbv = *reinterpret_cast<const f32x4*>(&mb_s[it * 64 + kh * 32 + s2 * 8 + hl * 4]);
        float p0 = EXP2F(scc[4 * s2 + 0] + mbv[0]);
        float p1 = EXP2F(scc[4 * s2 + 1] + mbv[1]);
        float p2 = EXP2F(scc[4 * s2 + 2] + mbv[2]);
        float p3 = EXP2F(scc[4 * s2 + 3] + mbv[3]);
        lsum += (p0 + p1) + (p2 + p3);
        w[s2][0] = cvtpk_bf16(p0, p1);
        w[s2][1] = cvtpk_bf16(p2, p3);
      }
    } else {
#pragma unroll
      for (int s2 = 0; s2 < 4; s2++) {
        float p0 = EXP2F(scc[4 * s2 + 0]);
        float p1 = EXP2F(scc[4 * s2 + 1]);
        float p2 = EXP2F(scc[4 * s2 + 2]);
        float p3 = EXP2F(scc[4 * s2 + 3]);
        lsum += (p0 + p1) + (p2 + p3);
        w[s2][0] = cvtpk_bf16(p0, p1);
        w[s2][1] = cvtpk_bf16(p2, p3);
      }
    }

    // redistribute P into PV B-fragments: pb[ks][j] = P[16ks+8hl+j][q31]
    bf16x8 pb[2];
#pragma unroll
    for (int ks = 0; ks < 2; ks++) {
      u32x2 r0 = __builtin_amdgcn_permlane32_swap(w[2 * ks][0], w[2 * ks + 1][0], false, false);
      u32x2 r1 = __builtin_amdgcn_permlane32_swap(w[2 * ks][1], w[2 * ks + 1][1], false, false);
      u32x4 uu;
      uu.x = r0.x; uu.y = r1.x; uu.z = r0.y; uu.w = r1.y;
      pb[ks] = __builtin_bit_cast(bf16x8, uu);
    }

    // PV (swapped): O^T[d][q] += V^T[d][k] * P[k][q]
    __builtin_amdgcn_s_setprio(1);
#pragma unroll
    for (int mt = 0; mt < 2; mt++)
#pragma unroll
      for (int ks = 0; ks < 2; ks++) {
        bf16x8 vf = *reinterpret_cast<const bf16x8*>(&Vd[cur][swz64((mt * 32 + q31) * 64 + kh * 32 + ks * 16 + hl * 8)]);
        oacc[mt] = __builtin_amdgcn_mfma_f32_32x32x16_bf16(vf, pb[ks], oacc[mt], 0, 0, 0);
      }
    __builtin_amdgcn_s_setprio(0);
  }

  // per-wave row sum for column q31
  lsum += __shfl_xor(lsum, 32);

  __syncthreads();   // nt may be odd: all waves done reading buf0 before Oc alias write

  // combine key-half partials: kh=1 writes O^T and l, kh=0 finishes
  float* Oc = qg ? (float*)&Vd[0][0] : (float*)&Kd[0][0];   // [64 d][32 q]
  if (kh == 1) {
#pragma unroll
    for (int mt = 0; mt < 2; mt++)
#pragma unroll
      for (int e = 0; e < 16; e++) {
        int d = mt * 32 + (e & 3) + (e >> 2) * 8 + hl * 4;
        Oc[d * 32 + q31] = oacc[mt][e];
      }
    if (hl == 0) Lc[qg][q31] = lsum;
  }
  __syncthreads();
  if (kh == 0) {
    float linv = 1.0f / (lsum + Lc[qg][q31]);
    uint16_t* Xr = X + ((size_t)b * S_LEN + q0 + q31) * EMB + hd * HDIM;
#pragma unroll
    for (int mt = 0; mt < 2; mt++)
#pragma unroll
      for (int s2 = 0; s2 < 4; s2++) {
        int d0 = mt * 32 + s2 * 8 + hl * 4;
        float v0 = (oacc[mt][4 * s2 + 0] + Oc[(d0 + 0) * 32 + q31]) * linv;
        float v1 = (oacc[mt][4 * s2 + 1] + Oc[(d0 + 1) * 32 + q31]) * linv;
        float v2 = (oacc[mt][4 * s2 + 2] + Oc[(d0 + 2) * 32 + q31]) * linv;
        float v3 = (oacc[mt][4 * s2 + 3] + Oc[(d0 + 3) * 32 + q31]) * linv;
        uint2 ww;
        ww.x = cvtpk_bf16(v0, v1);
        ww.y = cvtpk_bf16(v2, v3);
        *reinterpret_cast<uint2*>(Xr + d0) = ww;
      }
  }
}

// ---------------- Proj GEMM (verified r17): 64x64 tiles, bn-fast XCD decode ----------------
__global__ __launch_bounds__(256) void proj_gemm(const uint16_t* __restrict__ A,
                                                 const uint16_t* __restrict__ W,
                                                 const float* __restrict__ bias,
                                                 float* __restrict__ out) {
  __shared__ __align__(16) uint16_t As[64 * 64];
  __shared__ __align__(16) uint16_t Bs[64 * 64];
  const int t    = threadIdx.x;
  const int lane = t & 63;
  const int wv   = t >> 6;
  const int wr   = wv >> 1, wc = wv & 1;
  // bijective XCD swizzle, bn-fast: 768 = 8 * 96, 96 = 8 bm * 12 bn
  const int wg   = (blockIdx.x & 7) * 96 + (blockIdx.x >> 3);
  const int bm   = wg / 12;                  // 64 M tiles; 8 per XCD
  const int bn   = wg % 12;                  // 12 N tiles; all per XCD

  const uint16_t* Ag = A + (size_t)bm * 64 * 768;
  const uint16_t* Wg = W + (size_t)bn * 64 * 768;

  f32x4 zf = {0.f, 0.f, 0.f, 0.f};
  f32x4 acc[2][2];
#pragma unroll
  for (int m = 0; m < 2; m++)
#pragma unroll
    for (int n = 0; n < 2; n++) acc[m][n] = zf;

  for (int k0 = 0; k0 < 768; k0 += 64) {
#pragma unroll
    for (int j = 0; j < 2; j++) {
      int p = j * 256 + t;                   // chunk 0..511
      int r = p >> 3, x = p & 7;
      int scol = (x ^ (r & 7)) << 3;
      gload16(&As[p * 8], Ag + (size_t)r * 768 + k0 + scol);
      gload16(&Bs[p * 8], Wg + (size_t)r * 768 + k0 + scol);
    }
    __syncthreads();
#pragma unroll
    for (int kk = 0; kk < 2; kk++) {
      const int kc = kk * 32 + (lane >> 4) * 8;
      bf16x8 af[2], bf[2];
#pragma unroll
      for (int m = 0; m < 2; m++)
        af[m] = *reinterpret_cast<const bf16x8*>(&As[swz64((wr * 32 + m * 16 + (lane & 15)) * 64 + kc)]);
#pragma unroll
      for (int n = 0; n < 2; n++)
        bf[n] = *reinterpret_cast<const bf16x8*>(&Bs[swz64((wc * 32 + n * 16 + (lane & 15)) * 64 + kc)]);
#pragma unroll
      for (int m = 0; m < 2; m++)
#pragma unroll
        for (int n = 0; n < 2; n++)
          acc[m][n] = __builtin_amdgcn_mfma_f32_16x16x32_bf16(af[m], bf[n], acc[m][n], 0, 0, 0);
    }
    __syncthreads();
  }

#pragma unroll
  for (int n = 0; n < 2; n++) {
    const int f = bn * 64 + wc * 32 + n * 16 + (lane & 15);
    const float bv = bias[f];
#pragma unroll
    for (int m = 0; m < 2; m++)
#pragma unroll
      for (int r = 0; r < 4; r++) {
        int i = bm * 64 + wr * 32 + m * 16 + (lane >> 4) * 4 + r;
        out[(size_t)i * 768 + f] = acc[m][n][r] + bv;
      }
  }
}

extern "C" void kernel_launch(void* const* d_in, const int* in_sizes, int n_in,
                              void* d_out, int out_size, void* d_ws, size_t ws_size,
                              hipStream_t stream) {
  const float* inputs = (const float*)d_in[0];
  const int*   mask   = (const int*)d_in[1];
  const float* w_qkv  = (const float*)d_in[2];
  const float* b_qkv  = (const float*)d_in[3];
  const float* w_proj = (const float*)d_in[4];
  const float* b_proj = (const float*)d_in[5];
  float* out = (float*)d_out;

  uint16_t* a_bf  = (uint16_t*)d_ws;                    // 4096*768
  uint16_t* wq_bf = a_bf  + (size_t)4096 * 768;         // 2304*768
  uint16_t* wp_bf = wq_bf + (size_t)2304 * 768;         // 768*768
  uint16_t* q_bf  = wp_bf + (size_t)768 * 768;          // 24*2048*64
  uint16_t* k_bf  = q_bf  + (size_t)24 * 2048 * 64;     // compacted keys
  uint16_t* v_bf  = k_bf  + (size_t)24 * 2048 * 64;     // compacted, [B,H,D,Sc]
  uint16_t* x_bf  = v_bf  + (size_t)24 * 2048 * 64;     // 4096*768
  int*      cpos  = (int*)(x_bf + (size_t)4096 * 768);  // 2*2048 ints
  float*    mbc   = (float*)(cpos + 2 * 2048);          // 2*2048 floats
  int*      ntp   = (int*)(mbc + 2 * 2048);             // 2 ints
  int*      nbp   = ntp + 2;                            // 2 ints

  const int n0 = 4096 * 768 / 4, n1 = 2304 * 768 / 4, n2 = 768 * 768 / 4;
  const int cvtBlocks = (n0 + n1 + n2 + 255) / 256;     // 5376
  cvt_all<<<cvtBlocks + 2, 256, 0, stream>>>(
      (const float4*)inputs, (ushort4*)a_bf, n0,
      (const float4*)w_qkv,  (ushort4*)wq_bf, n1,
      (const float4*)w_proj, (ushort4*)wp_bf, n2,
      mask, cpos, mbc, ntp, nbp, cvtBlocks);
  pad_fill<<<2 * NHEAD, 256, 0, stream>>>(nbp, k_bf, v_bf);
  qkv_gemm<<<32 * 36, 256, 0, stream>>>(a_bf, wq_bf, b_qkv, cpos, q_bf, k_bf, v_bf);
  attn_kernel<<<24 * 32, 256, 0, stream>>>(q_bf, k_bf, v_bf, mbc, ntp, x_bf);
  proj_gemm<<<64 * 12, 256, 0, stream>>>(x_bf, wp_bf, b_proj, out);
}